// Round 10
// baseline (4646.210 us; speedup 1.0000x reference)
//
#include <hip/hip_runtime.h>

typedef _Float16 half8 __attribute__((ext_vector_type(8)));
typedef _Float16 half4v __attribute__((ext_vector_type(4)));
typedef float float4v __attribute__((ext_vector_type(4)));

#define HID 2048
#define EMBD 2048
#define BATCH 128
#define TSTEPS 256
#define STEP ((size_t)BATCH * HID)

// ---------------- small prep kernels ----------------
__global__ __launch_bounds__(256) void cast_f16_kernel(const float* __restrict__ src,
                                                       _Float16* __restrict__ dst, int n) {
    int i = (blockIdx.x * 256 + threadIdx.x) * 4;
    int stride = gridDim.x * 256 * 4;
    for (; i < n; i += stride) {
        float4v v = *(const float4v*)(src + i);
        half4v h;
        h[0] = (_Float16)v[0]; h[1] = (_Float16)v[1];
        h[2] = (_Float16)v[2]; h[3] = (_Float16)v[3];
        *(half4v*)(dst + i) = h;
    }
}

__global__ __launch_bounds__(256) void bias_kernel(const float* __restrict__ a,
                                                   const float* __restrict__ b,
                                                   float* __restrict__ dst) {
    int i = blockIdx.x * 256 + threadIdx.x;
    if (i < HID) dst[i] = a[i] + b[i];
}

// ---------------- Phase A: slots 1..256 of xb = gather(emb,x) @ W_ih^T + bias ----------
__global__ __launch_bounds__(256) void phaseA_kernel(const int* __restrict__ x,
                                                     const float* __restrict__ emb,
                                                     const _Float16* __restrict__ w16,
                                                     const float* __restrict__ bias,
                                                     _Float16* __restrict__ xproj) {
    __shared__ __align__(16) _Float16 As[128 * 64];
    __shared__ __align__(16) _Float16 Bs[128 * 64];

    const int tid = threadIdx.x;
    const int bx  = blockIdx.x;
    const int nt = bx & 15, mt = bx >> 4;
    const long m0 = (long)mt * 128;
    const long n0 = (long)nt * 128;
    const int lane = tid & 63, w = tid >> 6;
    const int ln15 = lane & 15, kg = lane >> 4;
    const int wr = (w >> 1) * 64, wc = (w & 1) * 64;

    int xr[4];
#pragma unroll
    for (int it = 0; it < 4; ++it) xr[it] = x[m0 + ((it * 256 + tid) >> 3)];

    float4v acc[4][4];
#pragma unroll
    for (int m = 0; m < 4; ++m)
#pragma unroll
        for (int n = 0; n < 4; ++n) acc[m][n] = (float4v){0.f, 0.f, 0.f, 0.f};

    for (int kt = 0; kt < 32; ++kt) {
        __syncthreads();
#pragma unroll
        for (int it = 0; it < 4; ++it) {
            int c = it * 256 + tid;
            const float* src = emb + (long)xr[it] * EMBD + kt * 64 + (c & 7) * 8;
            float4v v0 = *(const float4v*)src;
            float4v v1 = *(const float4v*)(src + 4);
            half8 hv;
#pragma unroll
            for (int q = 0; q < 4; ++q) { hv[q] = (_Float16)v0[q]; hv[4 + q] = (_Float16)v1[q]; }
            *(half8*)(&As[c * 8]) = hv;
        }
#pragma unroll
        for (int it = 0; it < 4; ++it) {
            int c = it * 256 + tid;
            const _Float16* src = w16 + (n0 + (c >> 3)) * (long)EMBD + kt * 64 + (c & 7) * 8;
            *(half8*)(&Bs[c * 8]) = *(const half8*)src;
        }
        __syncthreads();
#pragma unroll
        for (int kk = 0; kk < 2; ++kk) {
            half8 a[4], b[4];
#pragma unroll
            for (int m = 0; m < 4; ++m)
                a[m] = *(half8*)(&As[(wr + m * 16 + ln15) * 64 + kk * 32 + kg * 8]);
#pragma unroll
            for (int n = 0; n < 4; ++n)
                b[n] = *(half8*)(&Bs[(wc + n * 16 + ln15) * 64 + kk * 32 + kg * 8]);
            // swapped operands -> transposed fragment: lane holds 4 consecutive cols
#pragma unroll
            for (int m = 0; m < 4; ++m)
#pragma unroll
                for (int n = 0; n < 4; ++n)
                    acc[m][n] = __builtin_amdgcn_mfma_f32_16x16x32_f16(b[n], a[m], acc[m][n], 0, 0, 0);
        }
    }
#pragma unroll
    for (int m = 0; m < 4; ++m) {
        long mg = m0 + wr + m * 16 + ln15;
#pragma unroll
        for (int n = 0; n < 4; ++n) {
            int nb = (int)n0 + wc + n * 16 + kg * 4;
            float4v bv = *(const float4v*)(bias + nb);
            union { half4v h; unsigned long long u; } pk;
#pragma unroll
            for (int r = 0; r < 4; ++r) pk.h[r] = (_Float16)(acc[m][n][r] + bv[r]);
            *(unsigned long long*)(xproj + mg * HID + nb) = pk.u;
        }
    }
}

// ---------------- Phase B: persistent scan — wave-autonomous chunk-gated pipeline ----
// 256 blocks x 256 thr. gid=bx&3 owns rows [32g,+32); sub=bx>>2 owns cols [32c,+32).
// Wave (qr=w>>1, qc=w&1) = 16 rows x 16 cols x FULL K via swapped-operand MFMA
// (lane -> row ln15, 4 contiguous cols) -> one 8B h-store/lane, no LDS reduce, no
// __syncthreads in loop. Per-WAVE flags (256/group): wave stores its tile (sc1),
// vmcnt(0) (own store + overlapped next-bias prefetch), lane0 posts flag.
// Consumer: ONE batched poll (lane l reads u64 = both qr-flags of chunk l, ballot ->
// 64-bit ready mask), then 8 groups of 8 chunks, re-polling only unready groups --
// straggler wait overlaps with MFMA on ready chunks.
// Slot-chain (R9-proven): bias[s] in slot s+1 (sc1 reads keep it uncached);
// h_{s+1} -> slot s (written once, read cacheably post-flag -> L2-shared per XCD).
__global__ __launch_bounds__(256, 1) void scan_kernel(_Float16* __restrict__ xb,
                                                      const _Float16* __restrict__ whh,
                                                      float* __restrict__ hlast,
                                                      unsigned* __restrict__ flags) {
    __shared__ __align__(16) _Float16 Wl[32 * 2048];  // 128 KB

    const int tid = threadIdx.x;
    const int bx = blockIdx.x;
    const int gid = bx & 3, sub = bx >> 2;
    const int m0 = gid * 32, n0 = sub * 32;
    const int lane = tid & 63, w = tid >> 6;
    const int ln15 = lane & 15, kg = lane >> 4;
    const int qr = w >> 1, qc = w & 1;

    // stage W[n0..n0+32) x [0..2048): byte = col*4096 + ((k*2) ^ ((col&7)<<4))
    for (int it = 0; it < 32; ++it) {
        int c = it * 256 + tid;
        int col = c >> 8, ch = c & 255;
        half8 v = *(const half8*)(whh + (long)(n0 + col) * HID + ch * 8);
        *(half8*)((char*)Wl + col * 4096 + ((ch * 16) ^ ((col & 7) << 4))) = v;
    }
    __syncthreads();

    unsigned* gfl = flags + gid * 256;                     // 256 per-wave flags/group
    const unsigned long long* gfl64 = (const unsigned long long*)gfl;
    const size_t arow = (size_t)(m0 + qr * 16 + ln15);     // h row: load AND output
    const int wbyte = (qc * 16 + ln15) * 4096;             // W col (first operand row)
    const int swz = (ln15 & 7) << 4;
    const size_t oidx = arow * HID + n0 + qc * 16 + kg * 4;  // output 4-col base
    const int fidx = qr * 128 + sub * 2 + qc;              // this wave's flag slot

    // bias[0] prefetch (slot 1, sc1 bypass)
    unsigned long long xbits = __hip_atomic_load(
        (const unsigned long long*)(xb + STEP + oidx),
        __ATOMIC_RELAXED, __HIP_MEMORY_SCOPE_AGENT);

    for (int s = 0; s < TSTEPS; ++s) {
        float4v acc0 = (float4v){0.f, 0.f, 0.f, 0.f};
        float4v acc1 = (float4v){0.f, 0.f, 0.f, 0.f};
        if (s > 0) {
            const _Float16* hrow = xb + (size_t)(s - 1) * STEP + arow * HID;
            // batched poll: lane l covers chunk l (both qr-flags as one u64)
            unsigned long long v = __hip_atomic_load(gfl64 + qr * 64 + lane,
                                    __ATOMIC_RELAXED, __HIP_MEMORY_SCOPE_AGENT);
            bool ok = ((unsigned)v >= (unsigned)s) && ((unsigned)(v >> 32) >= (unsigned)s);
            unsigned long long mask = __ballot(ok);
#pragma unroll 1
            for (int g = 0; g < 8; ++g) {
                while (((mask >> (g * 8)) & 0xFFull) != 0xFFull) {
                    __builtin_amdgcn_s_sleep(1);
                    v = __hip_atomic_load(gfl64 + qr * 64 + lane,
                                          __ATOMIC_RELAXED, __HIP_MEMORY_SCOPE_AGENT);
                    ok = ((unsigned)v >= (unsigned)s) && ((unsigned)(v >> 32) >= (unsigned)s);
                    mask = __ballot(ok);
                }
                asm volatile("" ::: "memory");  // no hoisting h loads above readiness
#pragma unroll
                for (int q = 0; q < 8; ++q) {
                    int j = g * 8 + q;
                    half8 a = *(const half8*)(hrow + j * 32 + kg * 8);
                    int k2 = j * 64 + kg * 16;
                    half8 bw = *(half8*)((char*)Wl + wbyte + (k2 ^ swz));
                    if (q & 1) acc1 = __builtin_amdgcn_mfma_f32_16x16x32_f16(bw, a, acc1, 0, 0, 0);
                    else       acc0 = __builtin_amdgcn_mfma_f32_16x16x32_f16(bw, a, acc0, 0, 0, 0);
                }
            }
        }

        union { unsigned long long u; half4v h; } xbv; xbv.u = xbits;
        float o0 = tanhf(acc0[0] + acc1[0] + (float)xbv.h[0]);
        float o1 = tanhf(acc0[1] + acc1[1] + (float)xbv.h[1]);
        float o2 = tanhf(acc0[2] + acc1[2] + (float)xbv.h[2]);
        float o3 = tanhf(acc0[3] + acc1[3] + (float)xbv.h[3]);

        if (s < TSTEPS - 1) {
            // prefetch bias[s+1] (slot s+2) BEFORE the drain: overlaps store ack
            xbits = __hip_atomic_load(
                (const unsigned long long*)(xb + (size_t)(s + 2) * STEP + oidx),
                __ATOMIC_RELAXED, __HIP_MEMORY_SCOPE_AGENT);
            union { half4v h; unsigned long long u; } pk;
            pk.h[0] = (_Float16)o0; pk.h[1] = (_Float16)o1;
            pk.h[2] = (_Float16)o2; pk.h[3] = (_Float16)o3;
            __hip_atomic_store((unsigned long long*)(xb + (size_t)s * STEP + oidx),
                               pk.u, __ATOMIC_RELAXED, __HIP_MEMORY_SCOPE_AGENT);
            // wait own h-store ack (and bias prefetch, in parallel) then post flag
            asm volatile("s_waitcnt vmcnt(0)" ::: "memory");
            if (lane == 0)
                __hip_atomic_store(&gfl[fidx], (unsigned)(s + 1),
                                   __ATOMIC_RELAXED, __HIP_MEMORY_SCOPE_AGENT);
        } else {
            float4v f = {o0, o1, o2, o3};
            *(float4v*)(hlast + oidx) = f;
        }
    }
}

// ---------------- head ----------------
__global__ __launch_bounds__(64) void fc1_kernel(const float* __restrict__ hlast,
                                                 const float* __restrict__ w,
                                                 const float* __restrict__ b,
                                                 float* __restrict__ z) {
    int bb = blockIdx.x;
    int j = blockIdx.y * 64 + threadIdx.x;
    const float* hr = hlast + (long)bb * HID;
    const float* wr = w + (long)j * HID;
    float acc = 0.f;
    for (int k = 0; k < HID; k += 4) {
        float4v hv = *(const float4v*)(hr + k);
        float4v wv = *(const float4v*)(wr + k);
        acc += hv[0] * wv[0] + hv[1] * wv[1] + hv[2] * wv[2] + hv[3] * wv[3];
    }
    acc += b[j];
    z[bb * 256 + j] = fmaxf(acc, 0.f);
}

__global__ __launch_bounds__(256) void fc2_kernel(const float* __restrict__ z,
                                                  const float* __restrict__ w,
                                                  const float* __restrict__ b,
                                                  float* __restrict__ out) {
    __shared__ float red[4];
    int bb = blockIdx.x;
    int tid = threadIdx.x;
    float zv = z[bb * 256 + tid];
    for (int c = 0; c < 3; ++c) {
        float s = zv * w[c * 256 + tid];
        for (int off = 32; off > 0; off >>= 1) s += __shfl_down(s, off, 64);
        if ((tid & 63) == 0) red[tid >> 6] = s;
        __syncthreads();
        if (tid == 0) out[bb * 3 + c] = red[0] + red[1] + red[2] + red[3] + b[c];
        __syncthreads();
    }
}

// ---------------- launch ----------------
extern "C" void kernel_launch(void* const* d_in, const int* in_sizes, int n_in,
                              void* d_out, int out_size, void* d_ws, size_t ws_size,
                              hipStream_t stream) {
    const int*   x    = (const int*)d_in[0];
    const float* emb  = (const float*)d_in[1];
    const float* Wih  = (const float*)d_in[2];
    const float* Whh  = (const float*)d_in[3];
    const float* bih  = (const float*)d_in[4];
    const float* bhh  = (const float*)d_in[5];
    const float* fc1w = (const float*)d_in[6];
    const float* fc1b = (const float*)d_in[7];
    const float* fc2w = (const float*)d_in[8];
    const float* fc2b = (const float*)d_in[9];
    float* out = (float*)d_out;

    char* ws = (char*)d_ws;
    size_t off = 0;
    _Float16* xb    = (_Float16*)(ws + off); off += 257 * STEP * 2;         // 134.7 MB
    _Float16* wih16 = (_Float16*)(ws + off); off += (size_t)HID * EMBD * 2; // 8 MB
    _Float16* whh16 = (_Float16*)(ws + off); off += (size_t)HID * HID * 2;  // 8 MB
    float*    bias  = (float*)(ws + off);    off += (size_t)HID * 4;
    float*    hlast = (float*)(ws + off);    off += (size_t)BATCH * HID * 4;
    float*    z     = (float*)(ws + off);    off += (size_t)BATCH * 256 * 4;
    unsigned* flags = (unsigned*)(ws + off); off += 4 * 256 * 4;  // 4 KB

    hipMemsetAsync(flags, 0, 4 * 256 * 4, stream);

    cast_f16_kernel<<<4096, 256, 0, stream>>>(Wih, wih16, HID * EMBD);
    cast_f16_kernel<<<4096, 256, 0, stream>>>(Whh, whh16, HID * HID);
    bias_kernel<<<8, 256, 0, stream>>>(bih, bhh, bias);

    // phaseA writes bias[s] into slot s+1
    phaseA_kernel<<<4096, 256, 0, stream>>>(x, emb, wih16, bias, xb + STEP);

    void* args[] = {(void*)&xb, (void*)&whh16, (void*)&hlast, (void*)&flags};
    hipLaunchCooperativeKernel((const void*)scan_kernel, dim3(256), dim3(256), args, 0, stream);

    fc1_kernel<<<dim3(128, 4), 64, 0, stream>>>(hlast, fc1w, fc1b, z);
    fc2_kernel<<<BATCH, 256, 0, stream>>>(z, fc2w, fc2b, out);
}

// Round 11
// 2731.153 us; speedup vs baseline: 1.7012x; 1.7012x over previous
//
#include <hip/hip_runtime.h>

typedef _Float16 half8 __attribute__((ext_vector_type(8)));
typedef _Float16 half4v __attribute__((ext_vector_type(4)));
typedef float float4v __attribute__((ext_vector_type(4)));

#define HID 2048
#define EMBD 2048
#define BATCH 128
#define TSTEPS 256
#define STEP ((size_t)BATCH * HID)

// ---------------- small prep kernels ----------------
__global__ __launch_bounds__(256) void cast_f16_kernel(const float* __restrict__ src,
                                                       _Float16* __restrict__ dst, int n) {
    int i = (blockIdx.x * 256 + threadIdx.x) * 4;
    int stride = gridDim.x * 256 * 4;
    for (; i < n; i += stride) {
        float4v v = *(const float4v*)(src + i);
        half4v h;
        h[0] = (_Float16)v[0]; h[1] = (_Float16)v[1];
        h[2] = (_Float16)v[2]; h[3] = (_Float16)v[3];
        *(half4v*)(dst + i) = h;
    }
}

__global__ __launch_bounds__(256) void bias_kernel(const float* __restrict__ a,
                                                   const float* __restrict__ b,
                                                   float* __restrict__ dst) {
    int i = blockIdx.x * 256 + threadIdx.x;
    if (i < HID) dst[i] = a[i] + b[i];
}

// ---------------- Phase A: slots 1..256 of xb = gather(emb,x) @ W_ih^T + bias ----------
__global__ __launch_bounds__(256) void phaseA_kernel(const int* __restrict__ x,
                                                     const float* __restrict__ emb,
                                                     const _Float16* __restrict__ w16,
                                                     const float* __restrict__ bias,
                                                     _Float16* __restrict__ xproj) {
    __shared__ __align__(16) _Float16 As[128 * 64];
    __shared__ __align__(16) _Float16 Bs[128 * 64];

    const int tid = threadIdx.x;
    const int bx  = blockIdx.x;
    const int nt = bx & 15, mt = bx >> 4;
    const long m0 = (long)mt * 128;
    const long n0 = (long)nt * 128;
    const int lane = tid & 63, w = tid >> 6;
    const int ln15 = lane & 15, kg = lane >> 4;
    const int wr = (w >> 1) * 64, wc = (w & 1) * 64;

    int xr[4];
#pragma unroll
    for (int it = 0; it < 4; ++it) xr[it] = x[m0 + ((it * 256 + tid) >> 3)];

    float4v acc[4][4];
#pragma unroll
    for (int m = 0; m < 4; ++m)
#pragma unroll
        for (int n = 0; n < 4; ++n) acc[m][n] = (float4v){0.f, 0.f, 0.f, 0.f};

    for (int kt = 0; kt < 32; ++kt) {
        __syncthreads();
        // stage A: gather emb rows, f32 -> f16 (manual: conversion needed)
#pragma unroll
        for (int it = 0; it < 4; ++it) {
            int c = it * 256 + tid;
            const float* src = emb + (long)xr[it] * EMBD + kt * 64 + (c & 7) * 8;
            float4v v0 = *(const float4v*)src;
            float4v v1 = *(const float4v*)(src + 4);
            half8 hv;
#pragma unroll
            for (int q = 0; q < 4; ++q) { hv[q] = (_Float16)v0[q]; hv[4 + q] = (_Float16)v1[q]; }
            *(half8*)(&As[c * 8]) = hv;
        }
        // stage B: async global->LDS, 16B/lane; dest = wave-uniform base + lane*16
#pragma unroll
        for (int it = 0; it < 4; ++it) {
            int c = it * 256 + tid;
            const _Float16* src = w16 + (n0 + (c >> 3)) * (long)EMBD + kt * 64 + (c & 7) * 8;
            __builtin_amdgcn_global_load_lds((const __attribute__((address_space(1))) void*)src,
                                             (__attribute__((address_space(3))) void*)&Bs[c * 8],
                                             16, 0, 0);
        }
        __syncthreads();  // drains vmcnt (async LDS loads) + lgkm
#pragma unroll
        for (int kk = 0; kk < 2; ++kk) {
            half8 a[4], b[4];
#pragma unroll
            for (int m = 0; m < 4; ++m)
                a[m] = *(half8*)(&As[(wr + m * 16 + ln15) * 64 + kk * 32 + kg * 8]);
#pragma unroll
            for (int n = 0; n < 4; ++n)
                b[n] = *(half8*)(&Bs[(wc + n * 16 + ln15) * 64 + kk * 32 + kg * 8]);
            // swapped operands -> transposed fragment: lane holds 4 consecutive cols
#pragma unroll
            for (int m = 0; m < 4; ++m)
#pragma unroll
                for (int n = 0; n < 4; ++n)
                    acc[m][n] = __builtin_amdgcn_mfma_f32_16x16x32_f16(b[n], a[m], acc[m][n], 0, 0, 0);
        }
    }
#pragma unroll
    for (int m = 0; m < 4; ++m) {
        long mg = m0 + wr + m * 16 + ln15;
#pragma unroll
        for (int n = 0; n < 4; ++n) {
            int nb = (int)n0 + wc + n * 16 + kg * 4;
            float4v bv = *(const float4v*)(bias + nb);
            union { half4v h; unsigned long long u; } pk;
#pragma unroll
            for (int r = 0; r < 4; ++r) pk.h[r] = (_Float16)(acc[m][n][r] + bv[r]);
            *(unsigned long long*)(xproj + mg * HID + nb) = pk.u;
        }
    }
}

// ---------------- Phase B: persistent scan — flag gate + cacheable L2-shared h ------
// R9 structure (proven 1950us) with byte-packed single-line flags.
// 256 blocks x 256 thr. gid=bx&3 owns rows [32g,+32); sub=bx>>2 owns cols [32c,+32).
// Wave (pr=w>>1, kh=w&1): 16 rows x 32 cols x k-half; LDS part-reduce (stride 33).
// Buffer xb = 257 slots. bias[s] in slot s+1 (sc1 reads, never cached).
// h_{s+1} -> slot s (sc1; slot provably dead). Gate: 64 producer BYTE flags in ONE
// 64B line; SWAR test "no byte == s-1" (values at gate-s are in {s-1,s,s+1} by the
// drift<=1 argument). Post-gate h reads are plain cacheable (L2-shared per XCD).
__global__ __launch_bounds__(256, 1) void scan_kernel(_Float16* __restrict__ xb,
                                                      const _Float16* __restrict__ whh,
                                                      float* __restrict__ hlast,
                                                      unsigned char* __restrict__ flags) {
    __shared__ __align__(16) _Float16 Wl[32 * 2048];  // 128 KB
    __shared__ float part[4][16 * 33];

    const int tid = threadIdx.x;
    const int bx = blockIdx.x;
    const int gid = bx & 3, sub = bx >> 2;
    const int m0 = gid * 32, n0 = sub * 32;
    const int lane = tid & 63, w = tid >> 6;
    const int ln15 = lane & 15, kg = lane >> 4;
    const int pr = w >> 1, kh = w & 1;

    // stage W[n0..n0+32) x [0..2048): byte = col*4096 + ((k*2) ^ ((col&7)<<4))
    for (int it = 0; it < 32; ++it) {
        int c = it * 256 + tid;
        int col = c >> 8, ch = c & 255;
        half8 v = *(const half8*)(whh + (long)(n0 + col) * HID + ch * 8);
        *(half8*)((char*)Wl + col * 4096 + ((ch * 16) ^ ((col & 7) << 4))) = v;
    }
    __syncthreads();

    unsigned char* gfl = flags + gid * 64;                  // one 64B line per group
    const unsigned long long* gfl64 = (const unsigned long long*)gfl;
    const size_t arow = (size_t)(m0 + pr * 16 + ln15);      // h row this lane loads
    const int wb0 = ln15 * 4096, wb1 = (16 + ln15) * 4096;  // W LDS row bases
    const int swz = (ln15 & 7) << 4;
    const int kb = kh * 2048;                               // k-half byte offset
    const int rp = tid >> 7, ridx = tid & 127;              // reduce/output mapping
    const int rrow = ridx >> 3, rc4 = (ridx & 7) * 4;
    const size_t oidx = (size_t)(m0 + rp * 16 + rrow) * HID + n0 + rc4;

    for (int s = 0; s < TSTEPS; ++s) {
        // bias[s] from slot s+1 — sc1 bypass (keeps slot out of all caches)
        unsigned long long xbits = __hip_atomic_load(
            (const unsigned long long*)(xb + (size_t)(s + 1) * STEP + oidx),
            __ATOMIC_RELAXED, __HIP_MEMORY_SCOPE_AGENT);

        float4v acc0 = (float4v){0.f, 0.f, 0.f, 0.f};
        float4v acc1 = (float4v){0.f, 0.f, 0.f, 0.f};
        if (s > 0) {
            // ---- gate: no flag byte equals (s-1); one 64B line, sleepless SWAR poll
            unsigned long long pat =
                (unsigned long long)(unsigned char)(s - 1) * 0x0101010101010101ull;
            for (;;) {
                bool ok = true;
                if (lane < 8) {
                    unsigned long long v = __hip_atomic_load(gfl64 + lane,
                                            __ATOMIC_RELAXED, __HIP_MEMORY_SCOPE_AGENT);
                    unsigned long long xx = v ^ pat;
                    ok = !((xx - 0x0101010101010101ull) & ~xx & 0x8080808080808080ull);
                }
                if (__all(ok)) break;
            }
            asm volatile("" ::: "memory");        // no hoisting h loads above gate
            __builtin_amdgcn_sched_barrier(0);

            // ---- h_s from slot s-1: plain cacheable loads (L2-shared per XCD)
            const _Float16* hrow = xb + (size_t)(s - 1) * STEP + arow * HID + kh * 1024;
#pragma unroll
            for (int j = 0; j < 32; ++j) {
                half8 a = *(const half8*)(hrow + j * 32 + kg * 8);
                int k2 = kb + j * 64 + kg * 16;
                half8 b0 = *(half8*)((char*)Wl + wb0 + (k2 ^ swz));
                half8 b1 = *(half8*)((char*)Wl + wb1 + (k2 ^ swz));
                acc0 = __builtin_amdgcn_mfma_f32_16x16x32_f16(a, b0, acc0, 0, 0, 0);
                acc1 = __builtin_amdgcn_mfma_f32_16x16x32_f16(a, b1, acc1, 0, 0, 0);
            }
            // partials to LDS (stride 33)
#pragma unroll
            for (int r = 0; r < 4; ++r) {
                part[w][(kg * 4 + r) * 33 + ln15] = acc0[r];
                part[w][(kg * 4 + r) * 33 + 16 + ln15] = acc1[r];
            }
        }

        float s0 = 0.f, s1 = 0.f, s2 = 0.f, s3 = 0.f;
        if (s > 0) {
            __syncthreads();
            const float* p0 = &part[2 * rp][rrow * 33 + rc4];
            const float* p1 = &part[2 * rp + 1][rrow * 33 + rc4];
            s0 = p0[0] + p1[0]; s1 = p0[1] + p1[1];
            s2 = p0[2] + p1[2]; s3 = p0[3] + p1[3];
        }
        union { unsigned long long u; half4v h; } xbv; xbv.u = xbits;
        float o0 = tanhf(s0 + (float)xbv.h[0]);
        float o1 = tanhf(s1 + (float)xbv.h[1]);
        float o2 = tanhf(s2 + (float)xbv.h[2]);
        float o3 = tanhf(s3 + (float)xbv.h[3]);

        if (s < TSTEPS - 1) {
            // h_{s+1} -> slot s (sc1 fire-and-forget)
            union { half4v h; unsigned long long u; } pk;
            pk.h[0] = (_Float16)o0; pk.h[1] = (_Float16)o1;
            pk.h[2] = (_Float16)o2; pk.h[3] = (_Float16)o3;
            __hip_atomic_store((unsigned long long*)(xb + (size_t)s * STEP + oidx),
                               pk.u, __ATOMIC_RELAXED, __HIP_MEMORY_SCOPE_AGENT);
            // syncthreads drains vmcnt: all h stores acked at L3 before the flag.
            // Also the WAR guard for part[].
            __syncthreads();
            if (tid == 0)
                __hip_atomic_store(&gfl[sub], (unsigned char)(s + 1),
                                   __ATOMIC_RELAXED, __HIP_MEMORY_SCOPE_AGENT);
        } else {
            float4v f = {o0, o1, o2, o3};
            *(float4v*)(hlast + oidx) = f;
        }
    }
}

// ---------------- head ----------------
// fc1 tiled: 16 blocks x 8 batch rows; fc1w read ONCE per block (32MB total vs 256MB)
__global__ __launch_bounds__(256) void fc1_kernel(const float* __restrict__ hlast,
                                                  const float* __restrict__ w,
                                                  const float* __restrict__ b,
                                                  float* __restrict__ z) {
    __shared__ float hs[8][256];
    const int blk = blockIdx.x;     // 16
    const int j = threadIdx.x;      // 0..255 output col
    const int bb0 = blk * 8;
    float acc[8];
#pragma unroll
    for (int r = 0; r < 8; ++r) acc[r] = 0.f;
    const float* wr = w + (long)j * HID;
    const int sr = j >> 5, sc = (j & 31) * 8;  // staging map: 8 rows x 256 cols/tile

    for (int kt = 0; kt < 8; ++kt) {
        __syncthreads();
        float4v h0 = *(const float4v*)(hlast + (long)(bb0 + sr) * HID + kt * 256 + sc);
        float4v h1 = *(const float4v*)(hlast + (long)(bb0 + sr) * HID + kt * 256 + sc + 4);
        *(float4v*)&hs[sr][sc] = h0;
        *(float4v*)&hs[sr][sc + 4] = h1;
        __syncthreads();
        for (int k = 0; k < 256; k += 4) {
            float4v wv = *(const float4v*)(wr + kt * 256 + k);
#pragma unroll
            for (int r = 0; r < 8; ++r) {
                float4v hv = *(const float4v*)&hs[r][k];
                acc[r] += hv[0] * wv[0] + hv[1] * wv[1] + hv[2] * wv[2] + hv[3] * wv[3];
            }
        }
    }
    float bj = b[j];
#pragma unroll
    for (int r = 0; r < 8; ++r) z[(bb0 + r) * 256 + j] = fmaxf(acc[r] + bj, 0.f);
}

__global__ __launch_bounds__(256) void fc2_kernel(const float* __restrict__ z,
                                                  const float* __restrict__ w,
                                                  const float* __restrict__ b,
                                                  float* __restrict__ out) {
    __shared__ float red[4];
    int bb = blockIdx.x;
    int tid = threadIdx.x;
    float zv = z[bb * 256 + tid];
    for (int c = 0; c < 3; ++c) {
        float s = zv * w[c * 256 + tid];
        for (int off = 32; off > 0; off >>= 1) s += __shfl_down(s, off, 64);
        if ((tid & 63) == 0) red[tid >> 6] = s;
        __syncthreads();
        if (tid == 0) out[bb * 3 + c] = red[0] + red[1] + red[2] + red[3] + b[c];
        __syncthreads();
    }
}

// ---------------- launch ----------------
extern "C" void kernel_launch(void* const* d_in, const int* in_sizes, int n_in,
                              void* d_out, int out_size, void* d_ws, size_t ws_size,
                              hipStream_t stream) {
    const int*   x    = (const int*)d_in[0];
    const float* emb  = (const float*)d_in[1];
    const float* Wih  = (const float*)d_in[2];
    const float* Whh  = (const float*)d_in[3];
    const float* bih  = (const float*)d_in[4];
    const float* bhh  = (const float*)d_in[5];
    const float* fc1w = (const float*)d_in[6];
    const float* fc1b = (const float*)d_in[7];
    const float* fc2w = (const float*)d_in[8];
    const float* fc2b = (const float*)d_in[9];
    float* out = (float*)d_out;

    char* ws = (char*)d_ws;
    size_t off = 0;
    _Float16* xb    = (_Float16*)(ws + off); off += 257 * STEP * 2;         // 134.7 MB
    _Float16* wih16 = (_Float16*)(ws + off); off += (size_t)HID * EMBD * 2; // 8 MB
    _Float16* whh16 = (_Float16*)(ws + off); off += (size_t)HID * HID * 2;  // 8 MB
    float*    bias  = (float*)(ws + off);    off += (size_t)HID * 4;
    float*    hlast = (float*)(ws + off);    off += (size_t)BATCH * HID * 4;
    float*    z     = (float*)(ws + off);    off += (size_t)BATCH * 256 * 4;
    unsigned char* flags = (unsigned char*)(ws + off); off += 256;  // 4 groups x 64B

    hipMemsetAsync(flags, 0, 256, stream);

    cast_f16_kernel<<<4096, 256, 0, stream>>>(Wih, wih16, HID * EMBD);
    cast_f16_kernel<<<4096, 256, 0, stream>>>(Whh, whh16, HID * HID);
    bias_kernel<<<8, 256, 0, stream>>>(bih, bhh, bias);

    // phaseA writes bias[s] into slot s+1
    phaseA_kernel<<<4096, 256, 0, stream>>>(x, emb, wih16, bias, xb + STEP);

    void* args[] = {(void*)&xb, (void*)&whh16, (void*)&hlast, (void*)&flags};
    hipLaunchCooperativeKernel((const void*)scan_kernel, dim3(256), dim3(256), args, 0, stream);

    fc1_kernel<<<16, 256, 0, stream>>>(hlast, fc1w, fc1b, z);
    fc2_kernel<<<BATCH, 256, 0, stream>>>(z, fc2w, fc2b, out);
}